// Round 1
// baseline (790.607 us; speedup 1.0000x reference)
//
#include <hip/hip_runtime.h>
#include <stdint.h>

// XCiT cross-covariance attention, bf16-MFMA pipeline.
// Shapes: b=8, n=4096, c=1024, H=16, d=64. All GEMMs K=1024, NT layout.
//
// ws layout (elements):
//   xbf   [8][4096][1024] bf16           33,554,432
//   wbf   [4][1024][1024] bf16 (q,k,v,o)  4,194,304
//   qkv   [3][8][1024][4096] bf16       100,663,296   (w=0:Q w=1:K w=2:V, stored [m][n] i.e. transposed proj)
//   attn  [8*16][64][64] fp32               524,288
//   outb  [8][1024][4096] bf16           33,554,432   (== [b][4096][1024] row-major after reshape identity)
// total ~330 MB

typedef unsigned short u16;
typedef __attribute__((ext_vector_type(8))) short bf16x8;
typedef __attribute__((ext_vector_type(8))) u16 u16x8;
typedef __attribute__((ext_vector_type(4))) u16 u16x4;
typedef __attribute__((ext_vector_type(4))) float f32x4;

__device__ __forceinline__ float bf2f(u16 u) {
  union { unsigned int i; float f; } x;
  x.i = ((unsigned int)u) << 16;
  return x.f;
}
__device__ __forceinline__ u16 f2bf(float f) {  // RNE, inputs are finite
  union { float f; unsigned int i; } x;
  x.f = f;
  unsigned int u = x.i;
  u = u + 0x7fffu + ((u >> 16) & 1u);
  return (u16)(u >> 16);
}

// ---------------- cast fp32 -> bf16 (x and the 4 weight matrices) ----------------
__global__ __launch_bounds__(256) void cast_kernel(
    const float4* __restrict__ x, const float4* __restrict__ wq,
    const float4* __restrict__ wk, const float4* __restrict__ wv,
    const float4* __restrict__ wo, u16x4* __restrict__ xbf,
    u16x4* __restrict__ wbf) {
  long i = (long)blockIdx.x * 256 + threadIdx.x;  // float4 index; grid covers 8388608
  float4 v = x[i];
  u16x4 o;
  o[0] = f2bf(v.x); o[1] = f2bf(v.y); o[2] = f2bf(v.z); o[3] = f2bf(v.w);
  xbf[i] = o;
  if (i < 1048576) {  // 4 weights x 262144 float4s
    int sel = (int)(i >> 18);
    const float4* s = (sel == 0) ? wq : (sel == 1) ? wk : (sel == 2) ? wv : wo;
    float4 w = s[i & 262143];
    u16x4 ow;
    ow[0] = f2bf(w.x); ow[1] = f2bf(w.y); ow[2] = f2bf(w.z); ow[3] = f2bf(w.w);
    wbf[i] = ow;
  }
}

// ---------------- 128x128 NT bf16 MFMA GEMM, K=1024 ----------------
// C[m,n] = sum_k A[m,k]*B[n,k].  MODE 0: QKV proj (A=W[z%3], B=x[z/3], C bf16 ld 4096)
//                                MODE 1: out proj (A=outb[z],  B=Wo,    C fp32 ld 1024 + bias)
template <int MODE>
__global__ __launch_bounds__(256) void gemm_nt(const u16* __restrict__ A,
                                               const u16* __restrict__ B,
                                               void* __restrict__ C,
                                               const float* __restrict__ bias) {
  __shared__ u16 As[128 * 40];  // pad 32->40 elems (80B row stride, 16B-aligned, ~2-way banks)
  __shared__ u16 Bs[128 * 40];
  const int tid = threadIdx.x;
  const int lane = tid & 63;
  const int wave = tid >> 6;
  const int wm = (wave & 1) * 64;
  const int wn = (wave >> 1) * 64;
  const int m0 = blockIdx.y * 128;
  const int n0 = blockIdx.x * 128;

  long aoff, boff, coff;
  if (MODE == 0) {
    int b = blockIdx.z / 3, w = blockIdx.z - b * 3;
    aoff = (long)w * 1048576;
    boff = (long)b * 4194304;
    coff = ((long)w * 8 + b) * 4194304;
  } else {
    aoff = (long)blockIdx.z * 4194304;
    boff = 0;
    coff = (long)blockIdx.z * 4194304;
  }

  const u16* Ag = A + aoff + (long)(m0 + (tid >> 2)) * 1024 + (tid & 3) * 8;
  const u16* Bg = B + boff + (long)(n0 + (tid >> 2)) * 1024 + (tid & 3) * 8;
  const int lw = (tid >> 2) * 40 + (tid & 3) * 8;

  f32x4 acc[4][4];
  const f32x4 z4 = {0.f, 0.f, 0.f, 0.f};
#pragma unroll
  for (int i = 0; i < 4; i++)
#pragma unroll
    for (int j = 0; j < 4; j++) acc[i][j] = z4;

  const int fm = lane & 15;
  const int fk = (lane >> 4) * 8;

  for (int kt = 0; kt < 1024; kt += 32) {
    u16x8 a1 = *(const u16x8*)(Ag + kt);
    u16x8 a2 = *(const u16x8*)(Ag + kt + 64 * 1024);
    u16x8 b1 = *(const u16x8*)(Bg + kt);
    u16x8 b2 = *(const u16x8*)(Bg + kt + 64 * 1024);
    __syncthreads();
    *(u16x8*)&As[lw] = a1;
    *(u16x8*)&As[lw + 64 * 40] = a2;
    *(u16x8*)&Bs[lw] = b1;
    *(u16x8*)&Bs[lw + 64 * 40] = b2;
    __syncthreads();
    bf16x8 af[4], bfm[4];
#pragma unroll
    for (int i = 0; i < 4; i++)
      af[i] = *(const bf16x8*)&As[(wm + i * 16 + fm) * 40 + fk];
#pragma unroll
    for (int j = 0; j < 4; j++)
      bfm[j] = *(const bf16x8*)&Bs[(wn + j * 16 + fm) * 40 + fk];
#pragma unroll
    for (int i = 0; i < 4; i++)
#pragma unroll
      for (int j = 0; j < 4; j++)
        acc[i][j] = __builtin_amdgcn_mfma_f32_16x16x32_bf16(af[i], bfm[j],
                                                            acc[i][j], 0, 0, 0);
  }

  const int rq = (lane >> 4) * 4;
  if (MODE == 0) {
    u16* Cb = (u16*)C + coff;
#pragma unroll
    for (int i = 0; i < 4; i++)
#pragma unroll
      for (int j = 0; j < 4; j++)
#pragma unroll
        for (int r = 0; r < 4; r++) {
          int m = m0 + wm + i * 16 + rq + r;
          int n = n0 + wn + j * 16 + fm;
          Cb[(long)m * 4096 + n] = f2bf(acc[i][j][r]);
        }
  } else {
    float* Cf = (float*)C + coff;
#pragma unroll
    for (int j = 0; j < 4; j++) {
      float bv = bias[n0 + wn + j * 16 + fm];
#pragma unroll
      for (int i = 0; i < 4; i++)
#pragma unroll
        for (int r = 0; r < 4; r++) {
          int m = m0 + wm + i * 16 + rq + r;
          int n = n0 + wn + j * 16 + fm;
          Cf[(long)m * 1024 + n] = acc[i][j][r] + bv;
        }
    }
  }
}

// ---------------- fused: row L2-norms + K.Q^T (MFMA, K=4096) + scale + softmax ----------------
// one block per (b,h); attn[d][e] = softmax_e( (K_d . Q_e) * rk[d]*rq[e]*scale[h] )
__global__ __launch_bounds__(256) void attn_softmax(const u16* __restrict__ qkv,
                                                    const float* __restrict__ scale,
                                                    float* __restrict__ attn) {
  const int bh = blockIdx.x;
  const int b = bh >> 4, h = bh & 15;
  __shared__ u16 Ks[64 * 40];
  __shared__ u16 Qs[64 * 40];
  __shared__ float sq[2][64][4];
  __shared__ float rn[2][64];
  __shared__ float Ss[64][68];
  const u16* Qg = qkv + ((long)b * 1024 + h * 64) * 4096;
  const u16* Kg = qkv + 33554432L + ((long)b * 1024 + h * 64) * 4096;

  const int tid = threadIdx.x;
  const int lane = tid & 63, wave = tid >> 6;
  const int lrow = tid >> 2, lkc = tid & 3;
  const int lw = lrow * 40 + lkc * 8;
  const int fm = lane & 15, fk = (lane >> 4) * 8;

  float sk = 0.f, sqv = 0.f;
  f32x4 acc[4];
  const f32x4 z4 = {0.f, 0.f, 0.f, 0.f};
#pragma unroll
  for (int j = 0; j < 4; j++) acc[j] = z4;

  const u16* Kr = Kg + (long)lrow * 4096 + lkc * 8;
  const u16* Qr = Qg + (long)lrow * 4096 + lkc * 8;
  for (int kt = 0; kt < 4096; kt += 32) {
    u16x8 kv = *(const u16x8*)(Kr + kt);
    u16x8 qv = *(const u16x8*)(Qr + kt);
#pragma unroll
    for (int e = 0; e < 8; e++) {
      float fkk = bf2f(kv[e]); sk += fkk * fkk;
      float fq = bf2f(qv[e]);  sqv += fq * fq;
    }
    __syncthreads();
    *(u16x8*)&Ks[lw] = kv;
    *(u16x8*)&Qs[lw] = qv;
    __syncthreads();
    bf16x8 a = *(const bf16x8*)&Ks[(wave * 16 + fm) * 40 + fk];
#pragma unroll
    for (int j = 0; j < 4; j++) {
      bf16x8 bb = *(const bf16x8*)&Qs[(j * 16 + fm) * 40 + fk];
      acc[j] = __builtin_amdgcn_mfma_f32_16x16x32_bf16(a, bb, acc[j], 0, 0, 0);
    }
  }
  sq[0][lrow][lkc] = sk;   // K-row partial sumsq (4 partials per row)
  sq[1][lrow][lkc] = sqv;  // Q-row
  __syncthreads();
  if (tid < 128) {
    int which = tid >> 6, row = tid & 63;
    float s = sq[which][row][0] + sq[which][row][1] + sq[which][row][2] + sq[which][row][3];
    rn[which][row] = 1.0f / fmaxf(sqrtf(s), 1e-12f);  // F.normalize eps
  }
  __syncthreads();
  const float sc = scale[h];
#pragma unroll
  for (int j = 0; j < 4; j++)
#pragma unroll
    for (int r = 0; r < 4; r++) {
      int d = wave * 16 + (lane >> 4) * 4 + r;  // C row
      int e = j * 16 + fm;                      // C col
      Ss[d][e] = acc[j][r] * rn[0][d] * rn[1][e] * sc;
    }
  __syncthreads();
  if (tid < 64) {
    int d = tid;
    float mx = -1e30f;
#pragma unroll
    for (int e = 0; e < 64; e++) mx = fmaxf(mx, Ss[d][e]);
    float ex[64];
    float sum = 0.f;
#pragma unroll
    for (int e = 0; e < 64; e++) {
      ex[e] = __expf(Ss[d][e] - mx);
      sum += ex[e];
    }
    float inv = 1.0f / sum;
    float* out = attn + ((long)bh * 64 + d) * 64;
#pragma unroll
    for (int e = 0; e < 64; e++) out[e] = ex[e] * inv;
  }
}

// ---------------- out[d,n] = sum_e attn[d,e] * V[e,n]  (per (b,h), n-tile 256) ----------------
__global__ __launch_bounds__(256) void av_kernel(const float* __restrict__ attn,
                                                 const u16* __restrict__ qkv,
                                                 u16* __restrict__ outb) {
  const int bh = blockIdx.y;
  const int b = bh >> 4, h = bh & 15;
  const int n0 = blockIdx.x * 256;
  const int tid = threadIdx.x;
  __shared__ float As[64 * 64];  // transposed: As[e*64+d]
  const float* ag = attn + (long)bh * 4096;
#pragma unroll
  for (int i = 0; i < 4; i++) {
    int f0 = tid * 16 + i * 4;
    float4 v = *(const float4*)(ag + f0);
    int d = f0 >> 6;  // same d for all 4 (f0 % 64 <= 60)
    As[((f0 + 0) & 63) * 64 + d] = v.x;
    As[((f0 + 1) & 63) * 64 + d] = v.y;
    As[((f0 + 2) & 63) * 64 + d] = v.z;
    As[((f0 + 3) & 63) * 64 + d] = v.w;
  }
  __syncthreads();
  const u16* vg = qkv + 67108864L + ((long)b * 1024 + h * 64) * 4096 + n0 + tid;
  float acc[64];
#pragma unroll
  for (int d = 0; d < 64; d++) acc[d] = 0.f;
#pragma unroll 4
  for (int e = 0; e < 64; e++) {
    float vf = bf2f(vg[(long)e * 4096]);
    const float4* ar = (const float4*)&As[e * 64];
#pragma unroll
    for (int d4 = 0; d4 < 16; d4++) {
      float4 a = ar[d4];
      acc[d4 * 4 + 0] += a.x * vf;
      acc[d4 * 4 + 1] += a.y * vf;
      acc[d4 * 4 + 2] += a.z * vf;
      acc[d4 * 4 + 3] += a.w * vf;
    }
  }
  u16* og = outb + ((long)b * 1024 + h * 64) * 4096 + n0 + tid;
#pragma unroll
  for (int d = 0; d < 64; d++) og[(long)d * 4096] = f2bf(acc[d]);
}

extern "C" void kernel_launch(void* const* d_in, const int* in_sizes, int n_in,
                              void* d_out, int out_size, void* d_ws, size_t ws_size,
                              hipStream_t stream) {
  const float* x = (const float*)d_in[0];
  const float* Wq = (const float*)d_in[1];
  const float* Wk = (const float*)d_in[2];
  const float* Wv = (const float*)d_in[3];
  const float* scale = (const float*)d_in[4];
  const float* Wo = (const float*)d_in[5];
  const float* bo = (const float*)d_in[6];
  float* out = (float*)d_out;

  u16* xbf = (u16*)d_ws;                      // 33554432
  u16* wbf = xbf + 33554432;                  //  4194304
  u16* qkv = wbf + 4194304;                   // 100663296
  float* attn = (float*)(qkv + 100663296);    //   524288 floats
  u16* outb = (u16*)(attn + 524288);          // 33554432

  cast_kernel<<<32768, 256, 0, stream>>>((const float4*)x, (const float4*)Wq,
                                         (const float4*)Wk, (const float4*)Wv,
                                         (const float4*)Wo, (u16x4*)xbf,
                                         (u16x4*)wbf);
  gemm_nt<0><<<dim3(32, 8, 24), 256, 0, stream>>>(wbf, xbf, (void*)qkv, nullptr);
  attn_softmax<<<128, 256, 0, stream>>>(qkv, scale, attn);
  av_kernel<<<dim3(16, 128), 256, 0, stream>>>(attn, qkv, outb);
  gemm_nt<1><<<dim3(8, 32, 8), 256, 0, stream>>>(outb, wbf + 3 * 1048576,
                                                 (void*)out, bo);
}

// Round 2
// 716.606 us; speedup vs baseline: 1.1033x; 1.1033x over previous
//
#include <hip/hip_runtime.h>
#include <stdint.h>

// XCiT cross-covariance attention, bf16-MFMA pipeline. R2: m97-style
// global_load_lds GEMM staging (unpadded LDS, lane-ordered) + barrier-free
// attn K-loop (wave-private k-quarter, frags direct from global).
//
// ws layout (elements):
//   xbf   [8][4096][1024] bf16           33,554,432
//   wbf   [4][1024][1024] bf16 (q,k,v,o)  4,194,304
//   qkv   [3][8][1024][4096] bf16       100,663,296
//   attn  [8*16][64][64] fp32               524,288
//   outb  [8][1024][4096] bf16           33,554,432

typedef unsigned short u16;
typedef __attribute__((ext_vector_type(8))) short bf16x8;
typedef __attribute__((ext_vector_type(8))) u16 u16x8;
typedef __attribute__((ext_vector_type(4))) u16 u16x4;
typedef __attribute__((ext_vector_type(4))) float f32x4;

__device__ __forceinline__ float bf2f(u16 u) {
  union { unsigned int i; float f; } x;
  x.i = ((unsigned int)u) << 16;
  return x.f;
}
__device__ __forceinline__ u16 f2bf(float f) {  // RNE, inputs finite
  union { float f; unsigned int i; } x;
  x.f = f;
  unsigned int u = x.i;
  u = u + 0x7fffu + ((u >> 16) & 1u);
  return (u16)(u >> 16);
}

// async global->LDS, 16B per lane; LDS dest = wave-uniform base + lane*16,
// so every lane must pass base + lane*16 (our tile layout is lane-ordered).
__device__ __forceinline__ void gload16(const u16* g, u16* l) {
  __builtin_amdgcn_global_load_lds(
      (const __attribute__((address_space(1))) void*)g,
      (__attribute__((address_space(3))) void*)l, 16, 0, 0);
}

// ---------------- cast fp32 -> bf16 (x and the 4 weight matrices) ----------------
__global__ __launch_bounds__(256) void cast_kernel(
    const float4* __restrict__ x, const float4* __restrict__ wq,
    const float4* __restrict__ wk, const float4* __restrict__ wv,
    const float4* __restrict__ wo, u16x4* __restrict__ xbf,
    u16x4* __restrict__ wbf) {
  long i = (long)blockIdx.x * 256 + threadIdx.x;  // float4 index; covers 8388608
  float4 v = x[i];
  u16x4 o;
  o[0] = f2bf(v.x); o[1] = f2bf(v.y); o[2] = f2bf(v.z); o[3] = f2bf(v.w);
  xbf[i] = o;
  if (i < 1048576) {  // 4 weights x 262144 float4s
    int sel = (int)(i >> 18);
    const float4* s = (sel == 0) ? wq : (sel == 1) ? wk : (sel == 2) ? wv : wo;
    float4 w = s[i & 262143];
    u16x4 ow;
    ow[0] = f2bf(w.x); ow[1] = f2bf(w.y); ow[2] = f2bf(w.z); ow[3] = f2bf(w.w);
    wbf[i] = ow;
  }
}

// ---------------- 128x128 NT bf16 MFMA GEMM, K=1024 ----------------
// C[m,n] = sum_k A[m,k]*B[n,k].  MODE 0: QKV proj (A=W[z%3], B=x[z/3], C bf16 ld 4096)
//                                MODE 1: out proj (A=outb[z],  B=Wo,    C fp32 ld 1024 + bias)
template <int MODE>
__global__ __launch_bounds__(256) void gemm_nt(const u16* __restrict__ A,
                                               const u16* __restrict__ B,
                                               void* __restrict__ C,
                                               const float* __restrict__ bias) {
  __shared__ u16 As[128 * 32];  // unpadded: row stride 64B, lane-ordered for global_load_lds
  __shared__ u16 Bs[128 * 32];
  const int tid = threadIdx.x;
  const int lane = tid & 63;
  const int wave = tid >> 6;
  const int wm = (wave & 1) * 64;
  const int wn = (wave >> 1) * 64;
  const int m0 = blockIdx.y * 128;
  const int n0 = blockIdx.x * 128;

  long aoff, boff, coff;
  if (MODE == 0) {
    int b = blockIdx.z / 3, w = blockIdx.z - b * 3;
    aoff = (long)w * 1048576;
    boff = (long)b * 4194304;
    coff = ((long)w * 8 + b) * 4194304;
  } else {
    aoff = (long)blockIdx.z * 4194304;
    boff = 0;
    coff = (long)blockIdx.z * 4194304;
  }

  // thread t stages tile row (t>>2), k-chunk (t&3)*8; LDS elem = t*8 (byte t*16)
  const u16* Ag = A + aoff + (long)(m0 + (tid >> 2)) * 1024 + (tid & 3) * 8;
  const u16* Bg = B + boff + (long)(n0 + (tid >> 2)) * 1024 + (tid & 3) * 8;
  u16* Asw = As + tid * 8;
  u16* Bsw = Bs + tid * 8;

  f32x4 acc[4][4];
  const f32x4 z4 = {0.f, 0.f, 0.f, 0.f};
#pragma unroll
  for (int i = 0; i < 4; i++)
#pragma unroll
    for (int j = 0; j < 4; j++) acc[i][j] = z4;

  const int fm = lane & 15;
  const int fk = (lane >> 4) * 8;

  for (int kt = 0; kt < 1024; kt += 32) {
    __syncthreads();  // previous iteration's ds_reads done
    gload16(Ag + kt, Asw);
    gload16(Ag + kt + 64 * 1024, Asw + 64 * 32);
    gload16(Bg + kt, Bsw);
    gload16(Bg + kt + 64 * 1024, Bsw + 64 * 32);
    __syncthreads();  // compiler drains vmcnt before barrier
    bf16x8 af[4], bfm[4];
#pragma unroll
    for (int i = 0; i < 4; i++)
      af[i] = *(const bf16x8*)&As[(wm + i * 16 + fm) * 32 + fk];
#pragma unroll
    for (int j = 0; j < 4; j++)
      bfm[j] = *(const bf16x8*)&Bs[(wn + j * 16 + fm) * 32 + fk];
#pragma unroll
    for (int i = 0; i < 4; i++)
#pragma unroll
      for (int j = 0; j < 4; j++)
        acc[i][j] = __builtin_amdgcn_mfma_f32_16x16x32_bf16(af[i], bfm[j],
                                                            acc[i][j], 0, 0, 0);
  }

  const int rq = (lane >> 4) * 4;
  if (MODE == 0) {
    u16* Cb = (u16*)C + coff;
#pragma unroll
    for (int i = 0; i < 4; i++)
#pragma unroll
      for (int j = 0; j < 4; j++)
#pragma unroll
        for (int r = 0; r < 4; r++) {
          int m = m0 + wm + i * 16 + rq + r;
          int n = n0 + wn + j * 16 + fm;
          Cb[(long)m * 4096 + n] = f2bf(acc[i][j][r]);
        }
  } else {
    float* Cf = (float*)C + coff;
#pragma unroll
    for (int j = 0; j < 4; j++) {
      float bv = bias[n0 + wn + j * 16 + fm];
#pragma unroll
      for (int i = 0; i < 4; i++)
#pragma unroll
        for (int r = 0; r < 4; r++) {
          int m = m0 + wm + i * 16 + rq + r;
          int n = n0 + wn + j * 16 + fm;
          Cf[(long)m * 1024 + n] = acc[i][j][r] + bv;
        }
    }
  }
}

// ---------------- fused: row L2-norms + K.Q^T + scale + softmax ----------------
// one block per (b,h); each wave owns a k-quarter (1024 k), computes the full
// 64x64 partial S with frags loaded straight from global (no LDS, no barriers
// in the loop). Cross-wave reduce + norms + softmax at the end.
__global__ __launch_bounds__(256) void attn_softmax(const u16* __restrict__ qkv,
                                                    const float* __restrict__ scale,
                                                    float* __restrict__ attn) {
  const int bh = blockIdx.x;
  const int b = bh >> 4, h = bh & 15;
  const int tid = threadIdx.x, lane = tid & 63, wave = tid >> 6;
  __shared__ float Sw[4][64][66];   // per-wave partial S
  __shared__ float nsq[2][4][64];   // per-wave partial sumsq (0=K,1=Q)
  __shared__ float rn[2][64];
  const u16* Qg = qkv + ((long)b * 1024 + h * 64) * 4096;
  const u16* Kg = Qg + 33554432L;

  const int fm = lane & 15;
  const long kbase = (long)wave * 1024 + (lane >> 4) * 8;

  f32x4 acc[4][4];
  const f32x4 z4 = {0.f, 0.f, 0.f, 0.f};
#pragma unroll
  for (int i = 0; i < 4; i++)
#pragma unroll
    for (int j = 0; j < 4; j++) acc[i][j] = z4;
  float sk[4] = {0.f, 0.f, 0.f, 0.f}, sq[4] = {0.f, 0.f, 0.f, 0.f};

  for (int kt = 0; kt < 1024; kt += 32) {
    bf16x8 ak[4], aq[4];
#pragma unroll
    for (int i = 0; i < 4; i++) {
      ak[i] = *(const bf16x8*)(Kg + (long)(i * 16 + fm) * 4096 + kbase + kt);
      aq[i] = *(const bf16x8*)(Qg + (long)(i * 16 + fm) * 4096 + kbase + kt);
    }
#pragma unroll
    for (int i = 0; i < 4; i++) {
      const u16x8 kv = (u16x8)ak[i], qv = (u16x8)aq[i];
#pragma unroll
      for (int e = 0; e < 8; e++) {
        float fkk = bf2f(kv[e]); sk[i] += fkk * fkk;
        float fq = bf2f(qv[e]);  sq[i] += fq * fq;
      }
    }
#pragma unroll
    for (int i = 0; i < 4; i++)
#pragma unroll
      for (int j = 0; j < 4; j++)
        acc[i][j] = __builtin_amdgcn_mfma_f32_16x16x32_bf16(ak[i], aq[j],
                                                            acc[i][j], 0, 0, 0);
  }

  // reduce sumsq across the 4 lanes sharing a row (lane ^ 16, ^ 32)
#pragma unroll
  for (int i = 0; i < 4; i++) {
    sk[i] += __shfl_xor(sk[i], 16); sk[i] += __shfl_xor(sk[i], 32);
    sq[i] += __shfl_xor(sq[i], 16); sq[i] += __shfl_xor(sq[i], 32);
  }
  if (lane < 16) {
#pragma unroll
    for (int i = 0; i < 4; i++) {
      nsq[0][wave][i * 16 + lane] = sk[i];
      nsq[1][wave][i * 16 + lane] = sq[i];
    }
  }
  const int rq = (lane >> 4) * 4;
#pragma unroll
  for (int i = 0; i < 4; i++)
#pragma unroll
    for (int j = 0; j < 4; j++)
#pragma unroll
      for (int r = 0; r < 4; r++)
        Sw[wave][i * 16 + rq + r][j * 16 + fm] = acc[i][j][r];
  __syncthreads();
  if (tid < 128) {
    int which = tid >> 6, row = tid & 63;
    float s = nsq[which][0][row] + nsq[which][1][row] + nsq[which][2][row] +
              nsq[which][3][row];
    rn[which][row] = 1.0f / fmaxf(sqrtf(s), 1e-12f);  // F.normalize eps
  }
  __syncthreads();
  if (tid < 64) {
    const int d = tid;
    const float rk = rn[0][d] * scale[h];
    float row[64];
    float mx = -1e30f;
#pragma unroll
    for (int e = 0; e < 64; e++) {
      float s = Sw[0][d][e] + Sw[1][d][e] + Sw[2][d][e] + Sw[3][d][e];
      row[e] = s * rk * rn[1][e];
      mx = fmaxf(mx, row[e]);
    }
    float sum = 0.f;
#pragma unroll
    for (int e = 0; e < 64; e++) {
      row[e] = __expf(row[e] - mx);
      sum += row[e];
    }
    float inv = 1.0f / sum;
    float* out = attn + ((long)bh * 64 + d) * 64;
#pragma unroll
    for (int e = 0; e < 64; e++) out[e] = row[e] * inv;
  }
}

// ---------------- out[d,n] = sum_e attn[d,e] * V[e,n]  (per (b,h), n-tile 256) ----------------
__global__ __launch_bounds__(256) void av_kernel(const float* __restrict__ attn,
                                                 const u16* __restrict__ qkv,
                                                 u16* __restrict__ outb) {
  const int bh = blockIdx.y;
  const int b = bh >> 4, h = bh & 15;
  const int n0 = blockIdx.x * 256;
  const int tid = threadIdx.x;
  __shared__ float As[64 * 64];  // transposed: As[e*64+d]
  const float* ag = attn + (long)bh * 4096;
#pragma unroll
  for (int i = 0; i < 4; i++) {
    int f0 = tid * 16 + i * 4;
    float4 v = *(const float4*)(ag + f0);
    int d = f0 >> 6;
    As[((f0 + 0) & 63) * 64 + d] = v.x;
    As[((f0 + 1) & 63) * 64 + d] = v.y;
    As[((f0 + 2) & 63) * 64 + d] = v.z;
    As[((f0 + 3) & 63) * 64 + d] = v.w;
  }
  __syncthreads();
  const u16* vg = qkv + 67108864L + ((long)b * 1024 + h * 64) * 4096 + n0 + tid;
  float acc[64];
#pragma unroll
  for (int d = 0; d < 64; d++) acc[d] = 0.f;
#pragma unroll 4
  for (int e = 0; e < 64; e++) {
    float vf = bf2f(vg[(long)e * 4096]);
    const float4* ar = (const float4*)&As[e * 64];
#pragma unroll
    for (int d4 = 0; d4 < 16; d4++) {
      float4 a = ar[d4];
      acc[d4 * 4 + 0] += a.x * vf;
      acc[d4 * 4 + 1] += a.y * vf;
      acc[d4 * 4 + 2] += a.z * vf;
      acc[d4 * 4 + 3] += a.w * vf;
    }
  }
  u16* og = outb + ((long)b * 1024 + h * 64) * 4096 + n0 + tid;
#pragma unroll
  for (int d = 0; d < 64; d++) og[(long)d * 4096] = f2bf(acc[d]);
}

extern "C" void kernel_launch(void* const* d_in, const int* in_sizes, int n_in,
                              void* d_out, int out_size, void* d_ws, size_t ws_size,
                              hipStream_t stream) {
  const float* x = (const float*)d_in[0];
  const float* Wq = (const float*)d_in[1];
  const float* Wk = (const float*)d_in[2];
  const float* Wv = (const float*)d_in[3];
  const float* scale = (const float*)d_in[4];
  const float* Wo = (const float*)d_in[5];
  const float* bo = (const float*)d_in[6];
  float* out = (float*)d_out;

  u16* xbf = (u16*)d_ws;                      // 33554432
  u16* wbf = xbf + 33554432;                  //  4194304
  u16* qkv = wbf + 4194304;                   // 100663296
  float* attn = (float*)(qkv + 100663296);    //   524288 floats
  u16* outb = (u16*)(attn + 524288);          // 33554432

  cast_kernel<<<32768, 256, 0, stream>>>((const float4*)x, (const float4*)Wq,
                                         (const float4*)Wk, (const float4*)Wv,
                                         (const float4*)Wo, (u16x4*)xbf,
                                         (u16x4*)wbf);
  gemm_nt<0><<<dim3(32, 8, 24), 256, 0, stream>>>(wbf, xbf, (void*)qkv, nullptr);
  attn_softmax<<<128, 256, 0, stream>>>(qkv, scale, attn);
  av_kernel<<<dim3(16, 128), 256, 0, stream>>>(attn, qkv, outb);
  gemm_nt<1><<<dim3(8, 32, 8), 256, 0, stream>>>(outb, wbf + 3 * 1048576,
                                                 (void*)out, bo);
}

// Round 3
// 682.128 us; speedup vs baseline: 1.1590x; 1.0505x over previous
//
#include <hip/hip_runtime.h>
#include <stdint.h>

// XCiT cross-covariance attention, bf16-MFMA pipeline. R3:
//  - QKV split: Q,K projections channel-major (gemm MODE 0); V projection
//    token-major (MODE 2) so attn@V can run as an NT MFMA GEMM.
//  - attn: k-split x16 partial kernel (no in-loop barriers) + finalize
//    (norm + softmax -> bf16).
//  - av: MFMA (A=attn bf16 via LDS, B=V token-major from global, K=64).
//
// ws layout (u16 elems unless noted):
//   xbf   [8][4096][1024]                33,554,432   @ 0
//   wbf   [4][1024][1024] (q,k,v,o)       4,194,304   @ 33,554,432
//   qk    [2][8][1024][4096] (Q,K ch-major) 67,108,864 @ 37,748,736
//   vt    [8][4096][1024] (V token-major) 33,554,432  @ 104,857,600
//   attnP fp32 [16][128][64][64]          8,388,608 f @ byte 276,824,064
//   nsqP  fp32 [16][128][2][64]             262,144 f
//   attnb bf16 [128][64][64]                524,288
//   outb  aliases qk (Q,K dead after attn_partial)    @ 37,748,736

typedef unsigned short u16;
typedef __attribute__((ext_vector_type(8))) short bf16x8;
typedef __attribute__((ext_vector_type(8))) u16 u16x8;
typedef __attribute__((ext_vector_type(4))) u16 u16x4;
typedef __attribute__((ext_vector_type(4))) float f32x4;

__device__ __forceinline__ float bf2f(u16 u) {
  union { unsigned int i; float f; } x;
  x.i = ((unsigned int)u) << 16;
  return x.f;
}
__device__ __forceinline__ u16 f2bf(float f) {  // RNE, inputs finite
  union { float f; unsigned int i; } x;
  x.f = f;
  unsigned int u = x.i;
  u = u + 0x7fffu + ((u >> 16) & 1u);
  return (u16)(u >> 16);
}

// async global->LDS, 16B/lane; LDS dest is wave-uniform base + lane*16.
__device__ __forceinline__ void gload16(const u16* g, u16* l) {
  __builtin_amdgcn_global_load_lds(
      (const __attribute__((address_space(1))) void*)g,
      (__attribute__((address_space(3))) void*)l, 16, 0, 0);
}

// ---------------- cast fp32 -> bf16 (x and the 4 weight matrices) ----------------
__global__ __launch_bounds__(256) void cast_kernel(
    const float4* __restrict__ x, const float4* __restrict__ wq,
    const float4* __restrict__ wk, const float4* __restrict__ wv,
    const float4* __restrict__ wo, u16x4* __restrict__ xbf,
    u16x4* __restrict__ wbf) {
  long i = (long)blockIdx.x * 256 + threadIdx.x;  // float4 index; covers 8388608
  float4 v = x[i];
  u16x4 o;
  o[0] = f2bf(v.x); o[1] = f2bf(v.y); o[2] = f2bf(v.z); o[3] = f2bf(v.w);
  xbf[i] = o;
  if (i < 1048576) {  // 4 weights x 262144 float4s
    int sel = (int)(i >> 18);
    const float4* s = (sel == 0) ? wq : (sel == 1) ? wk : (sel == 2) ? wv : wo;
    float4 w = s[i & 262143];
    u16x4 ow;
    ow[0] = f2bf(w.x); ow[1] = f2bf(w.y); ow[2] = f2bf(w.z); ow[3] = f2bf(w.w);
    wbf[i] = ow;
  }
}

// ---------------- 128x128 NT bf16 MFMA GEMM, K=1024 ----------------
// C[m,n] = sum_k A[m,k]*B[n,k].
// MODE 0: Q,K proj (z=w*8+b, w in {0,1}): A=W[w], B=x[b], C bf16 ch-major ld 4096
// MODE 1: out proj (z=b): A=outb[b], B=Wo, C fp32 ld 1024 + bias
// MODE 2: V proj   (z=b): A=x[b], B=Wv, C bf16 token-major ld 1024
template <int MODE>
__global__ __launch_bounds__(256) void gemm_nt(const u16* __restrict__ A,
                                               const u16* __restrict__ B,
                                               void* __restrict__ C,
                                               const float* __restrict__ bias) {
  __shared__ u16 As[128 * 32];  // unpadded, lane-ordered for global_load_lds
  __shared__ u16 Bs[128 * 32];
  const int tid = threadIdx.x;
  const int lane = tid & 63;
  const int wave = tid >> 6;
  const int wm = (wave & 1) * 64;
  const int wn = (wave >> 1) * 64;
  const int m0 = blockIdx.y * 128;
  const int n0 = blockIdx.x * 128;

  long aoff, boff, coff;
  if (MODE == 0) {
    int w = blockIdx.z >> 3;
    int b = blockIdx.z & 7;
    aoff = (long)w * 1048576;
    boff = (long)b * 4194304;
    coff = (long)blockIdx.z * 4194304;
  } else {
    aoff = (long)blockIdx.z * 4194304;
    boff = 0;
    coff = (long)blockIdx.z * 4194304;
  }

  const u16* Ag = A + aoff + (long)(m0 + (tid >> 2)) * 1024 + (tid & 3) * 8;
  const u16* Bg = B + boff + (long)(n0 + (tid >> 2)) * 1024 + (tid & 3) * 8;
  u16* Asw = As + tid * 8;
  u16* Bsw = Bs + tid * 8;

  f32x4 acc[4][4];
  const f32x4 z4 = {0.f, 0.f, 0.f, 0.f};
#pragma unroll
  for (int i = 0; i < 4; i++)
#pragma unroll
    for (int j = 0; j < 4; j++) acc[i][j] = z4;

  const int fm = lane & 15;
  const int fk = (lane >> 4) * 8;

  for (int kt = 0; kt < 1024; kt += 32) {
    __syncthreads();
    gload16(Ag + kt, Asw);
    gload16(Ag + kt + 64 * 1024, Asw + 64 * 32);
    gload16(Bg + kt, Bsw);
    gload16(Bg + kt + 64 * 1024, Bsw + 64 * 32);
    __syncthreads();
    bf16x8 af[4], bfm[4];
#pragma unroll
    for (int i = 0; i < 4; i++)
      af[i] = *(const bf16x8*)&As[(wm + i * 16 + fm) * 32 + fk];
#pragma unroll
    for (int j = 0; j < 4; j++)
      bfm[j] = *(const bf16x8*)&Bs[(wn + j * 16 + fm) * 32 + fk];
#pragma unroll
    for (int i = 0; i < 4; i++)
#pragma unroll
      for (int j = 0; j < 4; j++)
        acc[i][j] = __builtin_amdgcn_mfma_f32_16x16x32_bf16(af[i], bfm[j],
                                                            acc[i][j], 0, 0, 0);
  }

  const int rq = (lane >> 4) * 4;
  if (MODE == 1) {
    float* Cf = (float*)C + coff;
#pragma unroll
    for (int j = 0; j < 4; j++) {
      float bv = bias[n0 + wn + j * 16 + fm];
#pragma unroll
      for (int i = 0; i < 4; i++)
#pragma unroll
        for (int r = 0; r < 4; r++) {
          int m = m0 + wm + i * 16 + rq + r;
          int n = n0 + wn + j * 16 + fm;
          Cf[(long)m * 1024 + n] = acc[i][j][r] + bv;
        }
    }
  } else {
    const int ldc = (MODE == 0) ? 4096 : 1024;
    u16* Cb = (u16*)C + coff;
#pragma unroll
    for (int i = 0; i < 4; i++)
#pragma unroll
      for (int j = 0; j < 4; j++)
#pragma unroll
        for (int r = 0; r < 4; r++) {
          int m = m0 + wm + i * 16 + rq + r;
          int n = n0 + wn + j * 16 + fm;
          Cb[(long)m * ldc + n] = f2bf(acc[i][j][r]);
        }
  }
}

// ---------------- attn partial: per (bh, kslice-of-4) block; 16 wave-slices ----------------
// Each wave owns 256 k, computes full 64x64 partial S + row sumsq, writes to ws.
__global__ __launch_bounds__(256) void attn_partial(const u16* __restrict__ qk,
                                                    float* __restrict__ attnP,
                                                    float* __restrict__ nsqP) {
  const int bh = blockIdx.x;
  const int b = bh >> 4, h = bh & 15;
  const int tid = threadIdx.x, lane = tid & 63, wave = tid >> 6;
  const int sl = blockIdx.y * 4 + wave;  // 0..15
  const u16* Qg = qk + (long)b * 4194304 + (long)h * 64 * 4096;
  const u16* Kg = Qg + 33554432L;

  const int fm = lane & 15;
  const long kbase = (long)sl * 256 + (lane >> 4) * 8;

  f32x4 acc[4][4];
  const f32x4 z4 = {0.f, 0.f, 0.f, 0.f};
#pragma unroll
  for (int i = 0; i < 4; i++)
#pragma unroll
    for (int j = 0; j < 4; j++) acc[i][j] = z4;
  float sk[4] = {0.f, 0.f, 0.f, 0.f}, sq[4] = {0.f, 0.f, 0.f, 0.f};

  for (int kt = 0; kt < 256; kt += 32) {
    bf16x8 ak[4], aq[4];
#pragma unroll
    for (int i = 0; i < 4; i++) {
      ak[i] = *(const bf16x8*)(Kg + (long)(i * 16 + fm) * 4096 + kbase + kt);
      aq[i] = *(const bf16x8*)(Qg + (long)(i * 16 + fm) * 4096 + kbase + kt);
    }
#pragma unroll
    for (int i = 0; i < 4; i++) {
      const u16x8 kv = (u16x8)ak[i], qv = (u16x8)aq[i];
#pragma unroll
      for (int e = 0; e < 8; e++) {
        float fkk = bf2f(kv[e]); sk[i] += fkk * fkk;
        float fq = bf2f(qv[e]);  sq[i] += fq * fq;
      }
    }
#pragma unroll
    for (int i = 0; i < 4; i++)
#pragma unroll
      for (int j = 0; j < 4; j++)
        acc[i][j] = __builtin_amdgcn_mfma_f32_16x16x32_bf16(ak[i], aq[j],
                                                            acc[i][j], 0, 0, 0);
  }

#pragma unroll
  for (int i = 0; i < 4; i++) {  // fold the 4 k-chunk lane groups
    sk[i] += __shfl_xor(sk[i], 16); sk[i] += __shfl_xor(sk[i], 32);
    sq[i] += __shfl_xor(sq[i], 16); sq[i] += __shfl_xor(sq[i], 32);
  }
  float* np = nsqP + ((long)sl * 128 + bh) * 128;
  if (lane < 16) {
#pragma unroll
    for (int i = 0; i < 4; i++) {
      np[i * 16 + lane] = sk[i];
      np[64 + i * 16 + lane] = sq[i];
    }
  }
  float* sp = attnP + ((long)sl * 128 + bh) * 4096;
  const int rq = (lane >> 4) * 4;
#pragma unroll
  for (int i = 0; i < 4; i++)
#pragma unroll
    for (int j = 0; j < 4; j++)
#pragma unroll
      for (int r = 0; r < 4; r++)
        sp[(i * 16 + rq + r) * 64 + j * 16 + fm] = acc[i][j][r];
}

// ---------------- finalize: sum 16 partials, norms, softmax -> bf16 ----------------
__global__ __launch_bounds__(128) void attn_finalize(const float* __restrict__ attnP,
                                                     const float* __restrict__ nsqP,
                                                     const float* __restrict__ scale,
                                                     u16* __restrict__ attnb) {
  const int bh = blockIdx.x;
  const int h = bh & 15;
  const int tid = threadIdx.x;
  __shared__ float rn[2][64];
  {
    int which = tid >> 6, row = tid & 63;
    float s = 0.f;
#pragma unroll
    for (int sl = 0; sl < 16; sl++)
      s += nsqP[((long)sl * 128 + bh) * 128 + which * 64 + row];
    rn[which][row] = 1.0f / fmaxf(sqrtf(s), 1e-12f);  // F.normalize eps
  }
  __syncthreads();
  if (tid < 64) {
    const int d = tid;
    float row[64];
#pragma unroll
    for (int e = 0; e < 64; e++) row[e] = 0.f;
    for (int sl = 0; sl < 16; sl++) {
      const float4* p =
          (const float4*)(attnP + ((long)sl * 128 + bh) * 4096 + d * 64);
#pragma unroll
      for (int e4 = 0; e4 < 16; e4++) {
        float4 v = p[e4];
        row[e4 * 4 + 0] += v.x;
        row[e4 * 4 + 1] += v.y;
        row[e4 * 4 + 2] += v.z;
        row[e4 * 4 + 3] += v.w;
      }
    }
    const float rk = rn[0][d] * scale[h];
    float mx = -1e30f;
#pragma unroll
    for (int e = 0; e < 64; e++) {
      row[e] = row[e] * rk * rn[1][e];
      mx = fmaxf(mx, row[e]);
    }
    float sum = 0.f;
#pragma unroll
    for (int e = 0; e < 64; e++) {
      row[e] = __expf(row[e] - mx);
      sum += row[e];
    }
    float inv = 1.0f / sum;
    u16* out = attnb + ((long)bh * 64 + d) * 64;
#pragma unroll
    for (int e = 0; e < 64; e++) out[e] = f2bf(row[e] * inv);
  }
}

// ---------------- av: out[d,n] = sum_e attn[d,e]*Vt[n,e], MFMA K=64 ----------------
__global__ __launch_bounds__(256) void av_mfma(const u16* __restrict__ attnb,
                                               const u16* __restrict__ vt,
                                               u16* __restrict__ outb) {
  const int bh = blockIdx.y;
  const int b = bh >> 4, h = bh & 15;
  const int n0 = blockIdx.x * 256;
  const int tid = threadIdx.x, lane = tid & 63, wave = tid >> 6;
  __shared__ u16 As[64 * 72];  // attn [d][e], pad 64->72 (row stride 144B)
  {
    const u16* src = attnb + (long)bh * 4096 + (tid >> 2) * 64 + (tid & 3) * 16;
    u16x8 v0 = *(const u16x8*)src;
    u16x8 v1 = *(const u16x8*)(src + 8);
    u16* dst = As + (tid >> 2) * 72 + (tid & 3) * 16;
    *(u16x8*)dst = v0;
    *(u16x8*)(dst + 8) = v1;
  }
  __syncthreads();
  const int fm = lane & 15;
  const int fe = (lane >> 4) * 8;
  const u16* Vg = vt + (long)b * 4194304 + h * 64 + fe;

  f32x4 acc[4][4];
  const f32x4 z4 = {0.f, 0.f, 0.f, 0.f};
#pragma unroll
  for (int i = 0; i < 4; i++)
#pragma unroll
    for (int j = 0; j < 4; j++) acc[i][j] = z4;

  bf16x8 af[4][2];
#pragma unroll
  for (int i = 0; i < 4; i++)
#pragma unroll
    for (int ks = 0; ks < 2; ks++)
      af[i][ks] = *(const bf16x8*)&As[(i * 16 + fm) * 72 + fe + ks * 32];

#pragma unroll
  for (int ks = 0; ks < 2; ks++)
#pragma unroll
    for (int j = 0; j < 4; j++) {
      int n = n0 + wave * 64 + j * 16 + fm;
      bf16x8 bf = *(const bf16x8*)(Vg + (long)n * 1024 + ks * 32);
#pragma unroll
      for (int i = 0; i < 4; i++)
        acc[i][j] = __builtin_amdgcn_mfma_f32_16x16x32_bf16(af[i][ks], bf,
                                                            acc[i][j], 0, 0, 0);
    }

  const int rq = (lane >> 4) * 4;
  u16* Ob = outb + ((long)b * 1024 + h * 64) * 4096;
#pragma unroll
  for (int i = 0; i < 4; i++)
#pragma unroll
    for (int j = 0; j < 4; j++)
#pragma unroll
      for (int r = 0; r < 4; r++) {
        int d = i * 16 + rq + r;
        int n = n0 + wave * 64 + j * 16 + fm;
        Ob[(long)d * 4096 + n] = f2bf(acc[i][j][r]);
      }
}

extern "C" void kernel_launch(void* const* d_in, const int* in_sizes, int n_in,
                              void* d_out, int out_size, void* d_ws, size_t ws_size,
                              hipStream_t stream) {
  const float* x = (const float*)d_in[0];
  const float* Wq = (const float*)d_in[1];
  const float* Wk = (const float*)d_in[2];
  const float* Wv = (const float*)d_in[3];
  const float* scale = (const float*)d_in[4];
  const float* Wo = (const float*)d_in[5];
  const float* bo = (const float*)d_in[6];
  float* out = (float*)d_out;

  u16* xbf = (u16*)d_ws;                     // 33,554,432
  u16* wbf = xbf + 33554432;                 //  4,194,304
  u16* qk = wbf + 4194304;                   // 67,108,864 (Q then K, ch-major)
  u16* vt = qk + 67108864;                   // 33,554,432 (token-major V)
  float* attnP = (float*)(vt + 33554432);    //  8,388,608 floats
  float* nsqP = attnP + 8388608;             //    262,144 floats
  u16* attnb = (u16*)(nsqP + 262144);        //    524,288
  u16* outb = qk;                            // alias: Q,K dead after attn_partial

  cast_kernel<<<32768, 256, 0, stream>>>((const float4*)x, (const float4*)Wq,
                                         (const float4*)Wk, (const float4*)Wv,
                                         (const float4*)Wo, (u16x4*)xbf,
                                         (u16x4*)wbf);
  gemm_nt<0><<<dim3(32, 8, 16), 256, 0, stream>>>(wbf, xbf, (void*)qk, nullptr);
  gemm_nt<2><<<dim3(8, 32, 8), 256, 0, stream>>>(xbf, wbf + 2 * 1048576,
                                                 (void*)vt, nullptr);
  attn_partial<<<dim3(128, 4), 256, 0, stream>>>(qk, attnP, nsqP);
  attn_finalize<<<128, 128, 0, stream>>>(attnP, nsqP, scale, attnb);
  av_mfma<<<dim3(16, 128), 256, 0, stream>>>(attnb, vt, outb);
  gemm_nt<1><<<dim3(8, 32, 8), 256, 0, stream>>>(outb, wbf + 3 * 1048576,
                                                 (void*)out, bo);
}